// Round 17
// baseline (231.134 us; speedup 1.0000x reference)
//
#include <hip/hip_runtime.h>
#include <hip/hip_bf16.h>
#include <cstdint>

// ---------------- problem constants (fixed by harness) ----------------
constexpr int CBATCH = 32;    // B
constexpr int CT = 800;       // T frames
constexpr int CD = 512;       // eprojs (K)
constexpr int CV = 1024;      // odim (V)
constexpr int CL = 100;       // max label len
constexpr int CM = CBATCH * CT;   // 25600 GEMM rows
constexpr int CS = 2 * CL + 1;    // 201 extended states
constexpr int CSPL = 256;         // ring row: 256 floats = 1024B
constexpr float NEGV = -1e30f;
constexpr float INV_LN2 = 1.4426950408889634f;
constexpr float LN2F = 0.6931471805599453f;

typedef __bf16 bf16x8 __attribute__((ext_vector_type(8)));
typedef float f32x4 __attribute__((ext_vector_type(4)));
typedef unsigned short ushort8 __attribute__((ext_vector_type(8)));

// ---------------- helpers ----------------
__device__ inline unsigned short f2bf(float f) {
  union { float f; unsigned u; } v; v.f = f;
  unsigned u = v.u;
  unsigned r = (u + 0x7fffu + ((u >> 16) & 1u)) >> 16;
  return (unsigned short)r;
}
__device__ inline float bf2f(unsigned short u) {
  unsigned x = (unsigned)u << 16;
  return __builtin_bit_cast(float, x);
}
__device__ inline float bitf(int x) { return __builtin_bit_cast(float, x); }

__device__ inline float fexp2(float x) { return __builtin_amdgcn_exp2f(x); }
__device__ inline float flog2(float x) { return __builtin_amdgcn_logf(x); }

// wave_shr:1 — lane i gets lane i-1; lane 0 gets `fill`. Pure VALU (DPP).
__device__ inline float dpp_shr1(float x, float fill) {
  int r = __builtin_amdgcn_update_dpp(__builtin_bit_cast(int, fill),
                                      __builtin_bit_cast(int, x),
                                      0x138, 0xF, 0xF, false);
  return __builtin_bit_cast(float, r);
}
__device__ inline int dpp_shr1_int(int x, int fill) {
  return __builtin_amdgcn_update_dpp(fill, x, 0x138, 0xF, 0xF, false);
}
// wave_shl:1 — lane i gets lane i+1; lane 63 gets `fill`.
__device__ inline float dpp_shl1(float x, float fill) {
  int r = __builtin_amdgcn_update_dpp(__builtin_bit_cast(int, fill),
                                      __builtin_bit_cast(int, x),
                                      0x130, 0xF, 0xF, false);
  return __builtin_bit_cast(float, r);
}
__device__ inline int dpp_shl1_int(int x, int fill) {
  return __builtin_amdgcn_update_dpp(fill, x, 0x130, 0xF, 0xF, false);
}

__device__ inline void gload_lds16(const void* g, void* l) {
  __builtin_amdgcn_global_load_lds(
      (const __attribute__((address_space(1))) unsigned int*)g,
      (__attribute__((address_space(3))) unsigned int*)l, 16, 0, 0);
}

// ---------------- 1. fp32 -> bf16 convert ----------------
__global__ void cvt_kernel(const float* __restrict__ in, unsigned short* __restrict__ out, int n4) {
  int i = blockIdx.x * blockDim.x + threadIdx.x;
  if (i < n4) {
    float4 v = reinterpret_cast<const float4*>(in)[i];
    ushort4 o;
    o.x = f2bf(v.x); o.y = f2bf(v.y); o.z = f2bf(v.z); o.w = f2bf(v.w);
    reinterpret_cast<ushort4*>(out)[i] = o;
  }
}

// ---------------- 2. bf16 MFMA GEMM (T2-swizzled LDS; round-11 verified) ----------
constexpr int GBK = 64;    // K-tile

__global__ __launch_bounds__(256, 2) void gemm_kernel(
    const unsigned short* __restrict__ A,   // [CM, CD] bf16 bits
    const unsigned short* __restrict__ Bt,  // [CV, CD] bf16 bits
    const float* __restrict__ bias,         // [CV]
    unsigned short* __restrict__ C)         // [CM, CV] bf16 bits
{
  __shared__ __align__(16) unsigned short As[128 * GBK];  // 16 KB, linear
  __shared__ __align__(16) unsigned short Bs[128 * GBK];
  const int tid = threadIdx.x;
  const int lane = tid & 63;
  const int wave = tid >> 6;          // 4 waves, 2x2 of 64x64
  const int wr = wave >> 1, wc = wave & 1;
  const int bm = blockIdx.x, bn = blockIdx.y;

  f32x4 acc[4][4] = {};

  for (int k0 = 0; k0 < CD; k0 += GBK) {
#pragma unroll
    for (int i = 0; i < 4; ++i) {
      int c = tid + 256 * i;
      int row = c >> 3;
      int scol = ((c & 7) ^ (row & 7)) * 8;   // pre-swizzled source col-block
      gload_lds16(&A[(size_t)(bm * 128 + row) * CD + k0 + scol], &As[c * 8]);
      gload_lds16(&Bt[(size_t)(bn * 128 + row) * CD + k0 + scol], &Bs[c * 8]);
    }
    __syncthreads();
#pragma unroll
    for (int kk = 0; kk < 2; ++kk) {
      bf16x8 af[4], bfr[4];
#pragma unroll
      for (int m = 0; m < 4; ++m) {
        int row = wr * 64 + m * 16 + (lane & 15);
        int cb = kk * 4 + (lane >> 4);
        af[m] = *reinterpret_cast<const bf16x8*>(
            &As[row * GBK + (cb ^ (row & 7)) * 8]);
      }
#pragma unroll
      for (int n = 0; n < 4; ++n) {
        int row = wc * 64 + n * 16 + (lane & 15);
        int cb = kk * 4 + (lane >> 4);
        bfr[n] = *reinterpret_cast<const bf16x8*>(
            &Bs[row * GBK + (cb ^ (row & 7)) * 8]);
      }
#pragma unroll
      for (int m = 0; m < 4; ++m)
#pragma unroll
        for (int n = 0; n < 4; ++n)
          acc[m][n] = __builtin_amdgcn_mfma_f32_16x16x32_bf16(af[m], bfr[n], acc[m][n], 0, 0, 0);
    }
    __syncthreads();
  }

  // epilogue: C layout col=lane&15, row=(lane>>4)*4+reg  [verified m89/m91]
  float bv[4];
#pragma unroll
  for (int n = 0; n < 4; ++n)
    bv[n] = bias[bn * 128 + wc * 64 + n * 16 + (lane & 15)];
#pragma unroll
  for (int m = 0; m < 4; ++m) {
    int rbase = bm * 128 + wr * 64 + m * 16 + (lane >> 4) * 4;
#pragma unroll
    for (int n = 0; n < 4; ++n) {
      int col = bn * 128 + wc * 64 + n * 16 + (lane & 15);
#pragma unroll
      for (int r = 0; r < 4; ++r)
        C[(size_t)(rbase + r) * CV + col] = f2bf(acc[m][n][r] + bv[n]);
    }
  }
}

// ---------------- 3. CTC recursion with FUSED lse+gather producers ----------------
// Round-16 lesson: 512-thread merge demotes the consumer's slots (VGPR 52) —
// stay at 256 threads / (256,1). This round: the separate lse_gather kernel
// (~15-18us, 52MB rd + 26MB wr) is deleted; the ctc PRODUCER waves (idle ~90%
// of the time) compute each row's lse (shfl-reduce over 16 bf16/lane) +
// ext-label gather + exp2 directly from bf16 logits (L3-resident) and write
// the p-row into the LDS ring. lpg buffer gone. Fwd consumer computes row-0
// lse inline once. Consumer loop/flag protocol/deferred renorm: verbatim
// round 15 (absmax 0, 43.7us).
constexpr int RRING = 64;                // LDS ring rows (64 KB)
constexpr int NCHUNKS = 51;              // 50 real chunks + 1 dummy (lookahead)

__global__ __launch_bounds__(256, 1) void ctc_kernel(
    const unsigned short* __restrict__ logits, const int* __restrict__ labels,
    const int* __restrict__ ilens, const int* __restrict__ llens,
    float* __restrict__ abuf, int* __restrict__ kbuf) {
  __shared__ __align__(16) float ring[RRING * CSPL];   // 64 KB
  __shared__ int ready[NCHUNKS + 1];
  __shared__ int done;
  const int bq = blockIdx.x;
  const int b = bq >> 1, dir = bq & 1;
  const int tid = threadIdx.x;
  const int lane = tid & 63;
  const int wid = tid >> 6;
  const int* lab = labels + b * CL;

  for (int i = tid; i < NCHUNKS + 1; i += 256) ready[i] = 0;
  if (tid == 0) done = 0;
  __syncthreads();

  if (wid == 0) {
    // ---------------- consumer ----------------
    const int ilen = ilens[b];
    const int ll = llens[b];
    const int s0 = lane * 4;
    float m1f = 0.f, m3f = 0.f;
    if (lane < 51) {
      int s1 = s0 + 1;
      if (s1 >= 3 && s1 < CS && lab[s1 >> 1] != lab[(s1 >> 1) - 1]) m1f = 1.f;
      int s3 = s0 + 3;
      if (s3 < CS && lab[s3 >> 1] != lab[(s3 >> 1) - 1]) m3f = 1.f;
    }
    float a0, a1, a2, a3;
    int kk = 0;
    if (dir == 0) {
      // inline lse+gather of row 0 (one-time): all lanes compute l
      const unsigned short* prow = logits + (size_t)(b * CT) * CV;
      ushort8 v0 = reinterpret_cast<const ushort8*>(prow)[lane * 2];
      ushort8 v1 = reinterpret_cast<const ushort8*>(prow)[lane * 2 + 1];
      float f[16];
#pragma unroll
      for (int q = 0; q < 8; ++q) { f[q] = bf2f(v0[q]); f[8 + q] = bf2f(v1[q]); }
      float m = f[0];
#pragma unroll
      for (int q = 1; q < 16; ++q) m = fmaxf(m, f[q]);
#pragma unroll
      for (int off = 32; off >= 1; off >>= 1) m = fmaxf(m, __shfl_xor(m, off));
      float s = 0.f;
#pragma unroll
      for (int q = 0; q < 16; ++q) s += __expf(f[q] - m);
#pragma unroll
      for (int off = 32; off >= 1; off >>= 1) s += __shfl_xor(s, off);
      const float l = m + __logf(s);
      float p0 = fexp2((bf2f(prow[0]) - l) * INV_LN2);
      float p1 = fexp2((bf2f(prow[lab[0]]) - l) * INV_LN2);
      a0 = (lane == 0) ? p0 : 0.f;
      a1 = (lane == 0 && ll > 0) ? p1 : 0.f;
      a2 = 0.f; a3 = 0.f;
    } else {
      const int e1 = 2 * ll, e2 = 2 * ll - 1;   // end states
      a0 = (s0 + 0 == e1 || s0 + 0 == e2) ? 1.f : 0.f;
      a1 = (s0 + 1 == e1 || s0 + 1 == e2) ? 1.f : 0.f;
      a2 = (s0 + 2 == e1 || s0 + 2 == e2) ? 1.f : 0.f;
      a3 = (s0 + 3 == e1 || s0 + 3 == e2) ? 1.f : 0.f;
    }

    volatile int* rdy = ready;
    while (rdy[0] == 0) {}
    asm volatile("" ::: "memory");
    // depth-8 named-reg prefetch: slots 0..7 (steps u=0..7)
    f32x4 lpA = *reinterpret_cast<const f32x4*>(&ring[0 * CSPL + lane * 4]);
    f32x4 lpB = *reinterpret_cast<const f32x4*>(&ring[1 * CSPL + lane * 4]);
    f32x4 lpC = *reinterpret_cast<const f32x4*>(&ring[2 * CSPL + lane * 4]);
    f32x4 lpD = *reinterpret_cast<const f32x4*>(&ring[3 * CSPL + lane * 4]);
    f32x4 lpE = *reinterpret_cast<const f32x4*>(&ring[4 * CSPL + lane * 4]);
    f32x4 lpF = *reinterpret_cast<const f32x4*>(&ring[5 * CSPL + lane * 4]);
    f32x4 lpG = *reinterpret_cast<const f32x4*>(&ring[6 * CSPL + lane * 4]);
    f32x4 lpH = *reinterpret_cast<const f32x4*>(&ring[7 * CSPL + lane * 4]);

// renorm (every 4th step): round-11-verified scale — lane max -> ~2^0.
#define RENORM4                                                           \
      {                                                                   \
        float mm_ = fmaxf(fmaxf(a0, a1), fmaxf(a2, a3));                  \
        int e_ = (__builtin_bit_cast(int, mm_) >> 23) & 0xFF;             \
        float sc_ = bitf((254 - e_) << 23);                               \
        a0 *= sc_; a1 *= sc_; a2 *= sc_; a3 *= sc_;                       \
        kk = K_ + e_ - 127;                                               \
      }

// forward step: u-th step processes frame t=1+u; renorm iff (J&3)==3
#define FSTEP(LP, J)                                                      \
    {                                                                     \
      const int u_ = uc + (J);                                            \
      f32x4 cur_ = LP;                                                    \
      LP = *reinterpret_cast<const f32x4*>(                               \
          &ring[((u_ + 8) & (RRING - 1)) * CSPL + lane * 4]);             \
      float nm_ = dpp_shr1(a3, 0.f);                                      \
      int nk_ = dpp_shr1_int(kk, (int)0xE0000000);                        \
      if (1 + u_ < ilen) {                                                \
        int K_ = nk_ > kk ? nk_ : kk;                                     \
        int ta_ = kk - K_ + 127;                                          \
        int tn_ = nk_ - K_ + 127;                                         \
        float fa_ = ta_ > 0 ? bitf(ta_ << 23) : 0.f;                      \
        float fn_ = tn_ > 0 ? bitf(tn_ << 23) : 0.f;                      \
        float na3_ = nm_ * fn_;                                           \
        float c0_ = __builtin_fmaf(a0, fa_, na3_);                        \
        float c1_ = __builtin_fmaf(a0 + a1, fa_, na3_ * m1f);             \
        float c2_ = (a1 + a2) * fa_;                                      \
        float c3_ = __builtin_fmaf(a1, m3f, a2 + a3) * fa_;               \
        a0 = c0_ * cur_[0]; a1 = c1_ * cur_[1];                           \
        a2 = c2_ * cur_[2]; a3 = c3_ * cur_[3];                           \
        if (((J) & 3) == 3) { RENORM4 } else { kk = K_; }                 \
      }                                                                   \
    }

// backward step: u-th step consumes q-row r=799-u; renorm iff (J&3)==3
#define BSTEP(LP, J)                                                      \
    {                                                                     \
      const int u_ = uc + (J);                                            \
      const int r_ = 799 - u_;                                            \
      f32x4 q_ = LP;                                                      \
      LP = *reinterpret_cast<const f32x4*>(                               \
          &ring[((u_ + 8) & (RRING - 1)) * CSPL + lane * 4]);             \
      float g0_ = a0 * q_[0], g1_ = a1 * q_[1];                           \
      float g2_ = a2 * q_[2], g3_ = a3 * q_[3];                           \
      float h_ = __builtin_fmaf(g1_, m1f, g0_);                           \
      float hn_ = dpp_shl1(h_, 0.f);                                      \
      int nk_ = dpp_shl1_int(kk, (int)0xE0000000);                        \
      if (r_ > 400 && r_ < ilen) {                                        \
        int K_ = nk_ > kk ? nk_ : kk;                                     \
        int ta_ = kk - K_ + 127;                                          \
        int tn_ = nk_ - K_ + 127;                                         \
        float fa_ = ta_ > 0 ? bitf(ta_ << 23) : 0.f;                      \
        float fn_ = tn_ > 0 ? bitf(tn_ << 23) : 0.f;                      \
        float c0_ = (g0_ + g1_) * fa_;                                    \
        float c1_ = __builtin_fmaf(g3_, m3f, g1_ + g2_) * fa_;            \
        float c2_ = (g2_ + g3_) * fa_;                                    \
        float c3_ = __builtin_fmaf(hn_, fn_, g3_ * fa_);                  \
        a0 = c0_; a1 = c1_; a2 = c2_; a3 = c3_;                           \
        if (((J) & 3) == 3) { RENORM4 } else { kk = K_; }                 \
      }                                                                   \
    }

    if (dir == 0) {
      for (int c = 0; c < 50; ++c) {
        while (rdy[c] == 0) {}
        while (rdy[c + 1] == 0) {}
        asm volatile("" ::: "memory");
        const int uc = 8 * c;
        FSTEP(lpA, 0) FSTEP(lpB, 1) FSTEP(lpC, 2) FSTEP(lpD, 3)
        FSTEP(lpE, 4) FSTEP(lpF, 5) FSTEP(lpG, 6) FSTEP(lpH, 7)
        asm volatile("s_waitcnt lgkmcnt(0)" ::: "memory");
        if (lane == 0) *(volatile int*)&done = c + 1;
      }
    } else {
      for (int c = 0; c < 50; ++c) {
        while (rdy[c] == 0) {}
        while (rdy[c + 1] == 0) {}
        asm volatile("" ::: "memory");
        const int uc = 8 * c;
        BSTEP(lpA, 0) BSTEP(lpB, 1) BSTEP(lpC, 2) BSTEP(lpD, 3)
        BSTEP(lpE, 4) BSTEP(lpF, 5) BSTEP(lpG, 6) BSTEP(lpH, 7)
        asm volatile("s_waitcnt lgkmcnt(0)" ::: "memory");
        if (lane == 0) *(volatile int*)&done = c + 1;
      }
    }
#undef FSTEP
#undef BSTEP
#undef RENORM4

    // store result fragment (all 64 lanes; lanes>=51 hold zeros)
    const int idx = bq * 64 + lane;
    f32x4 mv; mv[0] = a0; mv[1] = a1; mv[2] = a2; mv[3] = a3;
    reinterpret_cast<f32x4*>(abuf)[idx] = mv;
    kbuf[idx] = kk;
  } else {
    // ------- producers: fused lse+gather+exp2 per row, straight into ring -------
    const int p = wid - 1;                // 0..2
    for (int c = p; c < NCHUNKS; c += 3) {
      if (c >= 8) {
        while (*(volatile int*)&done < c - 7) {}   // ring backpressure
      }
      asm volatile("" ::: "memory");
      const int i0 = 8 * c;
      for (int j = 0; j < 8; ++j) {
        const int i = i0 + j;
        const int rf = dir ? (799 - i) : (1 + i);
        const unsigned short* prow = logits + (size_t)(b * CT + rf) * CV;
        ushort8 v0 = reinterpret_cast<const ushort8*>(prow)[lane * 2];
        ushort8 v1 = reinterpret_cast<const ushort8*>(prow)[lane * 2 + 1];
        float f[16];
#pragma unroll
        for (int q = 0; q < 8; ++q) { f[q] = bf2f(v0[q]); f[8 + q] = bf2f(v1[q]); }
        float m = f[0];
#pragma unroll
        for (int q = 1; q < 16; ++q) m = fmaxf(m, f[q]);
#pragma unroll
        for (int off = 32; off >= 1; off >>= 1) m = fmaxf(m, __shfl_xor(m, off));
        float s = 0.f;
#pragma unroll
        for (int q = 0; q < 16; ++q) s += __expf(f[q] - m);
#pragma unroll
        for (int off = 32; off >= 1; off >>= 1) s += __shfl_xor(s, off);
        const float l = m + __logf(s);      // natural-log lse, all lanes
        float4 o;
        if (lane < 51) {
          const int s0p = lane * 4;
          float vals[4];
#pragma unroll
          for (int jj = 0; jj < 4; ++jj) {
            int st = s0p + jj;
            if (st >= CS) { vals[jj] = NEGV; continue; }
            int e = (st & 1) ? lab[st >> 1] : 0;
            vals[jj] = (bf2f(prow[e]) - l) * INV_LN2;
          }
          o.x = fexp2(vals[0]); o.y = fexp2(vals[1]);
          o.z = fexp2(vals[2]); o.w = fexp2(vals[3]);
        } else {
          o.x = o.y = o.z = o.w = 0.f;
        }
        *reinterpret_cast<float4*>(&ring[(i & (RRING - 1)) * CSPL + lane * 4]) = o;
      }
      asm volatile("s_waitcnt lgkmcnt(0)" ::: "memory");
      if (lane == 0) *(volatile int*)&ready[c] = 1;
    }
  }
}

// ---------------- 4. combine: P_b = sum_s alpha_400(s)*beta_400(s) ----------------
__global__ void combine_kernel(const float* __restrict__ abuf,
                               const int* __restrict__ kbuf,
                               float* __restrict__ out) {
  const int b = blockIdx.x;
  const int lane = threadIdx.x;
  f32x4 am = reinterpret_cast<const f32x4*>(abuf)[(b * 2 + 0) * 64 + lane];
  f32x4 bm = reinterpret_cast<const f32x4*>(abuf)[(b * 2 + 1) * 64 + lane];
  int ak = kbuf[(b * 2 + 0) * 64 + lane];
  int bk = kbuf[(b * 2 + 1) * 64 + lane];
  float val = am[0] * bm[0] + am[1] * bm[1] + am[2] * bm[2] + am[3] * bm[3];
  int e = (val > 0.f) ? (ak + bk) : (int)0xC0000000;   // -2^30 sentinel
  int E = e;
#pragma unroll
  for (int off = 32; off >= 1; off >>= 1) E = max(E, __shfl_xor(E, off));
  int t = e - E + 127;
  float f = t > 0 ? __builtin_bit_cast(float, t << 23) : 0.f;
  float c = val * f;
#pragma unroll
  for (int off = 32; off >= 1; off >>= 1) c += __shfl_xor(c, off);
  if (lane == 0) {
    float ll2 = flog2(c) + (float)E;             // log2 likelihood
    atomicAdd(out, -ll2 * (LN2F / CBATCH));      // natural-log NLL
  }
}

// ---------------- launch ----------------
extern "C" void kernel_launch(void* const* d_in, const int* in_sizes, int n_in,
                              void* d_out, int out_size, void* d_ws, size_t ws_size,
                              hipStream_t stream) {
  const float* hpad = (const float*)d_in[0];
  const float* W    = (const float*)d_in[1];
  const float* bias = (const float*)d_in[2];
  const int* labels = (const int*)d_in[3];
  const int* ilens  = (const int*)d_in[4];
  const int* llens  = (const int*)d_in[5];
  float* out = (float*)d_out;

  char* ws = (char*)d_ws;
  size_t off = 0;
  auto alloc = [&](size_t bytes) -> void* {
    void* p = ws + off;
    off = (off + bytes + 255) & ~(size_t)255;
    return p;
  };
  unsigned short* Abf = (unsigned short*)alloc((size_t)CM * CD * 2);        // 26.2 MB
  unsigned short* Wbf = (unsigned short*)alloc((size_t)CV * CD * 2);        //  1.0 MB
  unsigned short* logits = (unsigned short*)alloc((size_t)CM * CV * 2);     // 52.4 MB bf16
  float* abuf = (float*)alloc((size_t)CBATCH * 2 * 64 * 4 * sizeof(float)); // 64 KB
  int*   kbuf = (int*)alloc((size_t)CBATCH * 2 * 64 * sizeof(int));         // 16 KB

  hipMemsetAsync(d_out, 0, sizeof(float), stream);

  cvt_kernel<<<(CM * CD / 4 + 255) / 256, 256, 0, stream>>>(hpad, Abf, CM * CD / 4);
  cvt_kernel<<<(CV * CD / 4 + 255) / 256, 256, 0, stream>>>(W, Wbf, CV * CD / 4);
  gemm_kernel<<<dim3(CM / 128, CV / 128), 256, 0, stream>>>(Abf, Wbf, bias, logits);
  ctc_kernel<<<CBATCH * 2, 256, 0, stream>>>(logits, labels, ilens, llens, abuf, kbuf);
  combine_kernel<<<CBATCH, 64, 0, stream>>>(abuf, kbuf, out);
}

// Round 18
// 113.141 us; speedup vs baseline: 2.0429x; 2.0429x over previous
//
#include <hip/hip_runtime.h>
#include <hip/hip_bf16.h>
#include <cstdint>

// ---------------- problem constants (fixed by harness) ----------------
constexpr int CBATCH = 32;    // B
constexpr int CT = 800;       // T frames
constexpr int CD = 512;       // eprojs (K)
constexpr int CV = 1024;      // odim (V)
constexpr int CL = 100;       // max label len
constexpr int CM = CBATCH * CT;   // 25600 GEMM rows
constexpr int CS = 2 * CL + 1;    // 201 extended states
constexpr int CSPL = 256;         // padded row: 256 floats = 1024B
constexpr float NEGV = -1e30f;
constexpr float INV_LN2 = 1.4426950408889634f;
constexpr float LN2F = 0.6931471805599453f;

typedef __bf16 bf16x8 __attribute__((ext_vector_type(8)));
typedef float f32x4 __attribute__((ext_vector_type(4)));
typedef unsigned short ushort8 __attribute__((ext_vector_type(8)));

// ---------------- helpers ----------------
__device__ inline unsigned short f2bf(float f) {
  union { float f; unsigned u; } v; v.f = f;
  unsigned u = v.u;
  unsigned r = (u + 0x7fffu + ((u >> 16) & 1u)) >> 16;
  return (unsigned short)r;
}
__device__ inline float bf2f(unsigned short u) {
  unsigned x = (unsigned)u << 16;
  return __builtin_bit_cast(float, x);
}
__device__ inline float bitf(int x) { return __builtin_bit_cast(float, x); }

__device__ inline float fexp2(float x) { return __builtin_amdgcn_exp2f(x); }
__device__ inline float flog2(float x) { return __builtin_amdgcn_logf(x); }

// wave_shr:1 — lane i gets lane i-1; lane 0 gets `fill`. Pure VALU (DPP).
__device__ inline float dpp_shr1(float x, float fill) {
  int r = __builtin_amdgcn_update_dpp(__builtin_bit_cast(int, fill),
                                      __builtin_bit_cast(int, x),
                                      0x138, 0xF, 0xF, false);
  return __builtin_bit_cast(float, r);
}
__device__ inline int dpp_shr1_int(int x, int fill) {
  return __builtin_amdgcn_update_dpp(fill, x, 0x138, 0xF, 0xF, false);
}
// wave_shl:1 — lane i gets lane i+1; lane 63 gets `fill`.
__device__ inline float dpp_shl1(float x, float fill) {
  int r = __builtin_amdgcn_update_dpp(__builtin_bit_cast(int, fill),
                                      __builtin_bit_cast(int, x),
                                      0x130, 0xF, 0xF, false);
  return __builtin_bit_cast(float, r);
}
__device__ inline int dpp_shl1_int(int x, int fill) {
  return __builtin_amdgcn_update_dpp(fill, x, 0x130, 0xF, 0xF, false);
}

__device__ inline void gload_lds16(const void* g, void* l) {
  __builtin_amdgcn_global_load_lds(
      (const __attribute__((address_space(1))) unsigned int*)g,
      (__attribute__((address_space(3))) unsigned int*)l, 16, 0, 0);
}

// ---------------- 1. fp32 -> bf16 convert ----------------
__global__ void cvt_kernel(const float* __restrict__ in, unsigned short* __restrict__ out, int n4) {
  int i = blockIdx.x * blockDim.x + threadIdx.x;
  if (i < n4) {
    float4 v = reinterpret_cast<const float4*>(in)[i];
    ushort4 o;
    o.x = f2bf(v.x); o.y = f2bf(v.y); o.z = f2bf(v.z); o.w = f2bf(v.w);
    reinterpret_cast<ushort4*>(out)[i] = o;
  }
}

// ---------------- 2. bf16 MFMA GEMM (T2-swizzled LDS; round-11 verified) ----------
constexpr int GBK = 64;    // K-tile

__global__ __launch_bounds__(256, 2) void gemm_kernel(
    const unsigned short* __restrict__ A,   // [CM, CD] bf16 bits
    const unsigned short* __restrict__ Bt,  // [CV, CD] bf16 bits
    const float* __restrict__ bias,         // [CV]
    unsigned short* __restrict__ C)         // [CM, CV] bf16 bits
{
  __shared__ __align__(16) unsigned short As[128 * GBK];  // 16 KB, linear
  __shared__ __align__(16) unsigned short Bs[128 * GBK];
  const int tid = threadIdx.x;
  const int lane = tid & 63;
  const int wave = tid >> 6;          // 4 waves, 2x2 of 64x64
  const int wr = wave >> 1, wc = wave & 1;
  const int bm = blockIdx.x, bn = blockIdx.y;

  f32x4 acc[4][4] = {};

  for (int k0 = 0; k0 < CD; k0 += GBK) {
#pragma unroll
    for (int i = 0; i < 4; ++i) {
      int c = tid + 256 * i;
      int row = c >> 3;
      int scol = ((c & 7) ^ (row & 7)) * 8;   // pre-swizzled source col-block
      gload_lds16(&A[(size_t)(bm * 128 + row) * CD + k0 + scol], &As[c * 8]);
      gload_lds16(&Bt[(size_t)(bn * 128 + row) * CD + k0 + scol], &Bs[c * 8]);
    }
    __syncthreads();
#pragma unroll
    for (int kk = 0; kk < 2; ++kk) {
      bf16x8 af[4], bfr[4];
#pragma unroll
      for (int m = 0; m < 4; ++m) {
        int row = wr * 64 + m * 16 + (lane & 15);
        int cb = kk * 4 + (lane >> 4);
        af[m] = *reinterpret_cast<const bf16x8*>(
            &As[row * GBK + (cb ^ (row & 7)) * 8]);
      }
#pragma unroll
      for (int n = 0; n < 4; ++n) {
        int row = wc * 64 + n * 16 + (lane & 15);
        int cb = kk * 4 + (lane >> 4);
        bfr[n] = *reinterpret_cast<const bf16x8*>(
            &Bs[row * GBK + (cb ^ (row & 7)) * 8]);
      }
#pragma unroll
      for (int m = 0; m < 4; ++m)
#pragma unroll
        for (int n = 0; n < 4; ++n)
          acc[m][n] = __builtin_amdgcn_mfma_f32_16x16x32_bf16(af[m], bfr[n], acc[m][n], 0, 0, 0);
    }
    __syncthreads();
  }

  // epilogue: C layout col=lane&15, row=(lane>>4)*4+reg  [verified m89/m91]
  float bv[4];
#pragma unroll
  for (int n = 0; n < 4; ++n)
    bv[n] = bias[bn * 128 + wc * 64 + n * 16 + (lane & 15)];
#pragma unroll
  for (int m = 0; m < 4; ++m) {
    int rbase = bm * 128 + wr * 64 + m * 16 + (lane >> 4) * 4;
#pragma unroll
    for (int n = 0; n < 4; ++n) {
      int col = bn * 128 + wc * 64 + n * 16 + (lane & 15);
#pragma unroll
      for (int r = 0; r < 4; ++r)
        C[(size_t)(rbase + r) * CV + col] = f2bf(acc[m][n][r] + bv[n]);
    }
  }
}

// ---------------- 3. fused lse + gather -> LINEAR probabilities ----------
__global__ void lse_gather_kernel(const unsigned short* __restrict__ C,
                                  const int* __restrict__ labels,
                                  float* __restrict__ lpg) {
  const int wave = threadIdx.x >> 6, lane = threadIdx.x & 63;
  const int row = blockIdx.x * 4 + wave;   // bt
  const int b = row / CT;
  const unsigned short* p = C + (size_t)row * CV;
  ushort8 v0 = reinterpret_cast<const ushort8*>(p)[lane * 2];
  ushort8 v1 = reinterpret_cast<const ushort8*>(p)[lane * 2 + 1];
  float f[16];
#pragma unroll
  for (int i = 0; i < 8; ++i) { f[i] = bf2f(v0[i]); f[8 + i] = bf2f(v1[i]); }
  float m = f[0];
#pragma unroll
  for (int i = 1; i < 16; ++i) m = fmaxf(m, f[i]);
#pragma unroll
  for (int off = 32; off >= 1; off >>= 1) m = fmaxf(m, __shfl_xor(m, off));
  float s = 0.f;
#pragma unroll
  for (int i = 0; i < 16; ++i) s += __expf(f[i] - m);
#pragma unroll
  for (int off = 32; off >= 1; off >>= 1) s += __shfl_xor(s, off);
  const float l = m + __logf(s);           // natural-log lse

  float4 o;
  if (lane < 51) {
    const int* lab = labels + b * CL;
    const int s0 = lane * 4;
    float vals[4];
#pragma unroll
    for (int j = 0; j < 4; ++j) {
      int st = s0 + j;
      if (st >= CS) { vals[j] = NEGV; continue; }
      int e = (st & 1) ? lab[st >> 1] : 0;
      vals[j] = (bf2f(p[e]) - l) * INV_LN2;
    }
    o.x = fexp2(vals[0]); o.y = fexp2(vals[1]);
    o.z = fexp2(vals[2]); o.w = fexp2(vals[3]);
  } else {
    o.x = o.y = o.z = o.w = 0.f;
  }
  reinterpret_cast<float4*>(lpg + (size_t)row * CSPL)[lane] = o;
}

// ---------------- 4. CTC bidirectional recursion (block-float linear) ----------------
// Round-15 verified build (absmax 0, ctc 43.7us): 64 blocks (batch x dir),
// producer/consumer wave split, depth-8 named-reg LDS prefetch, per-lane
// block-float with deferred renorm (every 4th step; kk=max on others).
constexpr int RRING = 64;                // LDS ring rows (64 KB)
constexpr int NCHUNKS = 51;              // 50 real chunks + 1 dummy (lookahead)

__global__ __launch_bounds__(256, 1) void ctc_kernel(
    const float* __restrict__ lpg, const int* __restrict__ labels,
    const int* __restrict__ ilens, const int* __restrict__ llens,
    float* __restrict__ abuf, int* __restrict__ kbuf) {
  __shared__ __align__(16) float ring[RRING * CSPL];   // 64 KB
  __shared__ int ready[NCHUNKS + 1];
  __shared__ int done;
  const int bq = blockIdx.x;
  const int b = bq >> 1, dir = bq & 1;
  const int tid = threadIdx.x;
  const int lane = tid & 63;
  const int wid = tid >> 6;
  const float* base = lpg + (size_t)b * CT * CSPL;

  for (int i = tid; i < NCHUNKS + 1; i += 256) ready[i] = 0;
  if (tid == 0) done = 0;
  __syncthreads();

  if (wid == 0) {
    // ---------------- consumer ----------------
    const int ilen = ilens[b];
    const int ll = llens[b];
    const int* lab = labels + b * CL;
    const int s0 = lane * 4;
    float m1f = 0.f, m3f = 0.f;
    if (lane < 51) {
      int s1 = s0 + 1;
      if (s1 >= 3 && s1 < CS && lab[s1 >> 1] != lab[(s1 >> 1) - 1]) m1f = 1.f;
      int s3 = s0 + 3;
      if (s3 < CS && lab[s3 >> 1] != lab[(s3 >> 1) - 1]) m3f = 1.f;
    }
    float a0, a1, a2, a3;
    int kk = 0;
    if (dir == 0) {
      f32x4 r0 = reinterpret_cast<const f32x4*>(base)[lane];
      a0 = (lane == 0) ? r0[0] : 0.f;
      a1 = (lane == 0 && ll > 0) ? r0[1] : 0.f;
      a2 = 0.f; a3 = 0.f;
    } else {
      const int e1 = 2 * ll, e2 = 2 * ll - 1;   // end states
      a0 = (s0 + 0 == e1 || s0 + 0 == e2) ? 1.f : 0.f;
      a1 = (s0 + 1 == e1 || s0 + 1 == e2) ? 1.f : 0.f;
      a2 = (s0 + 2 == e1 || s0 + 2 == e2) ? 1.f : 0.f;
      a3 = (s0 + 3 == e1 || s0 + 3 == e2) ? 1.f : 0.f;
    }

    volatile int* rdy = ready;
    while (rdy[0] == 0) {}
    asm volatile("" ::: "memory");
    // depth-8 named-reg prefetch: slots 0..7 (steps u=0..7)
    f32x4 lpA = *reinterpret_cast<const f32x4*>(&ring[0 * CSPL + lane * 4]);
    f32x4 lpB = *reinterpret_cast<const f32x4*>(&ring[1 * CSPL + lane * 4]);
    f32x4 lpC = *reinterpret_cast<const f32x4*>(&ring[2 * CSPL + lane * 4]);
    f32x4 lpD = *reinterpret_cast<const f32x4*>(&ring[3 * CSPL + lane * 4]);
    f32x4 lpE = *reinterpret_cast<const f32x4*>(&ring[4 * CSPL + lane * 4]);
    f32x4 lpF = *reinterpret_cast<const f32x4*>(&ring[5 * CSPL + lane * 4]);
    f32x4 lpG = *reinterpret_cast<const f32x4*>(&ring[6 * CSPL + lane * 4]);
    f32x4 lpH = *reinterpret_cast<const f32x4*>(&ring[7 * CSPL + lane * 4]);

// renorm (every 4th step): round-11-verified scale — lane max -> ~2^0.
#define RENORM4                                                           \
      {                                                                   \
        float mm_ = fmaxf(fmaxf(a0, a1), fmaxf(a2, a3));                  \
        int e_ = (__builtin_bit_cast(int, mm_) >> 23) & 0xFF;             \
        float sc_ = bitf((254 - e_) << 23);                               \
        a0 *= sc_; a1 *= sc_; a2 *= sc_; a3 *= sc_;                       \
        kk = K_ + e_ - 127;                                               \
      }

// forward step: u-th step processes frame t=1+u; renorm iff (J&3)==3
#define FSTEP(LP, J)                                                      \
    {                                                                     \
      const int u_ = uc + (J);                                            \
      f32x4 cur_ = LP;                                                    \
      LP = *reinterpret_cast<const f32x4*>(                               \
          &ring[((u_ + 8) & (RRING - 1)) * CSPL + lane * 4]);             \
      float nm_ = dpp_shr1(a3, 0.f);                                      \
      int nk_ = dpp_shr1_int(kk, (int)0xE0000000);                        \
      if (1 + u_ < ilen) {                                                \
        int K_ = nk_ > kk ? nk_ : kk;                                     \
        int ta_ = kk - K_ + 127;                                          \
        int tn_ = nk_ - K_ + 127;                                         \
        float fa_ = ta_ > 0 ? bitf(ta_ << 23) : 0.f;                      \
        float fn_ = tn_ > 0 ? bitf(tn_ << 23) : 0.f;                      \
        float na3_ = nm_ * fn_;                                           \
        float c0_ = __builtin_fmaf(a0, fa_, na3_);                        \
        float c1_ = __builtin_fmaf(a0 + a1, fa_, na3_ * m1f);             \
        float c2_ = (a1 + a2) * fa_;                                      \
        float c3_ = __builtin_fmaf(a1, m3f, a2 + a3) * fa_;               \
        a0 = c0_ * cur_[0]; a1 = c1_ * cur_[1];                           \
        a2 = c2_ * cur_[2]; a3 = c3_ * cur_[3];                           \
        if (((J) & 3) == 3) { RENORM4 } else { kk = K_; }                 \
      }                                                                   \
    }

// backward step: u-th step consumes q-row r=799-u; renorm iff (J&3)==3
#define BSTEP(LP, J)                                                      \
    {                                                                     \
      const int u_ = uc + (J);                                            \
      const int r_ = 799 - u_;                                            \
      f32x4 q_ = LP;                                                      \
      LP = *reinterpret_cast<const f32x4*>(                               \
          &ring[((u_ + 8) & (RRING - 1)) * CSPL + lane * 4]);             \
      float g0_ = a0 * q_[0], g1_ = a1 * q_[1];                           \
      float g2_ = a2 * q_[2], g3_ = a3 * q_[3];                           \
      float h_ = __builtin_fmaf(g1_, m1f, g0_);                           \
      float hn_ = dpp_shl1(h_, 0.f);                                      \
      int nk_ = dpp_shl1_int(kk, (int)0xE0000000);                        \
      if (r_ > 400 && r_ < ilen) {                                        \
        int K_ = nk_ > kk ? nk_ : kk;                                     \
        int ta_ = kk - K_ + 127;                                          \
        int tn_ = nk_ - K_ + 127;                                         \
        float fa_ = ta_ > 0 ? bitf(ta_ << 23) : 0.f;                      \
        float fn_ = tn_ > 0 ? bitf(tn_ << 23) : 0.f;                      \
        float c0_ = (g0_ + g1_) * fa_;                                    \
        float c1_ = __builtin_fmaf(g3_, m3f, g1_ + g2_) * fa_;            \
        float c2_ = (g2_ + g3_) * fa_;                                    \
        float c3_ = __builtin_fmaf(hn_, fn_, g3_ * fa_);                  \
        a0 = c0_; a1 = c1_; a2 = c2_; a3 = c3_;                           \
        if (((J) & 3) == 3) { RENORM4 } else { kk = K_; }                 \
      }                                                                   \
    }

    if (dir == 0) {
      for (int c = 0; c < 50; ++c) {
        while (rdy[c] == 0) {}
        while (rdy[c + 1] == 0) {}
        asm volatile("" ::: "memory");
        const int uc = 8 * c;
        FSTEP(lpA, 0) FSTEP(lpB, 1) FSTEP(lpC, 2) FSTEP(lpD, 3)
        FSTEP(lpE, 4) FSTEP(lpF, 5) FSTEP(lpG, 6) FSTEP(lpH, 7)
        asm volatile("s_waitcnt lgkmcnt(0)" ::: "memory");
        if (lane == 0) *(volatile int*)&done = c + 1;
      }
    } else {
      for (int c = 0; c < 50; ++c) {
        while (rdy[c] == 0) {}
        while (rdy[c + 1] == 0) {}
        asm volatile("" ::: "memory");
        const int uc = 8 * c;
        BSTEP(lpA, 0) BSTEP(lpB, 1) BSTEP(lpC, 2) BSTEP(lpD, 3)
        BSTEP(lpE, 4) BSTEP(lpF, 5) BSTEP(lpG, 6) BSTEP(lpH, 7)
        asm volatile("s_waitcnt lgkmcnt(0)" ::: "memory");
        if (lane == 0) *(volatile int*)&done = c + 1;
      }
    }
#undef FSTEP
#undef BSTEP
#undef RENORM4

    // store result fragment (all 64 lanes; lanes>=51 hold zeros)
    const int idx = bq * 64 + lane;
    f32x4 mv; mv[0] = a0; mv[1] = a1; mv[2] = a2; mv[3] = a3;
    reinterpret_cast<f32x4*>(abuf)[idx] = mv;
    kbuf[idx] = kk;
  } else {
    // ---------------- producers: stream 51 chunks into the ring ----------------
    const int p = wid - 1;                // 0..2
    for (int c = p; c < NCHUNKS; c += 3) {
      if (c >= 8) {
        while (*(volatile int*)&done < c - 7) {}   // ring backpressure
      }
      asm volatile("" ::: "memory");
      const int i0 = 8 * c;
      const float* src = base + (size_t)(dir ? (799 - i0) : (1 + i0)) * CSPL;
      const ptrdiff_t strd = dir ? -(ptrdiff_t)CSPL : (ptrdiff_t)CSPL;
      f32x4 v0 = reinterpret_cast<const f32x4*>(src + 0 * strd)[lane];
      f32x4 v1 = reinterpret_cast<const f32x4*>(src + 1 * strd)[lane];
      f32x4 v2 = reinterpret_cast<const f32x4*>(src + 2 * strd)[lane];
      f32x4 v3 = reinterpret_cast<const f32x4*>(src + 3 * strd)[lane];
      f32x4 v4 = reinterpret_cast<const f32x4*>(src + 4 * strd)[lane];
      f32x4 v5 = reinterpret_cast<const f32x4*>(src + 5 * strd)[lane];
      f32x4 v6 = reinterpret_cast<const f32x4*>(src + 6 * strd)[lane];
      f32x4 v7 = reinterpret_cast<const f32x4*>(src + 7 * strd)[lane];
      float* dst = &ring[((i0) & (RRING - 1)) * CSPL + lane * 4];
      *reinterpret_cast<f32x4*>(dst + 0 * CSPL) = v0;
      *reinterpret_cast<f32x4*>(dst + 1 * CSPL) = v1;
      *reinterpret_cast<f32x4*>(dst + 2 * CSPL) = v2;
      *reinterpret_cast<f32x4*>(dst + 3 * CSPL) = v3;
      *reinterpret_cast<f32x4*>(dst + 4 * CSPL) = v4;
      *reinterpret_cast<f32x4*>(dst + 5 * CSPL) = v5;
      *reinterpret_cast<f32x4*>(dst + 6 * CSPL) = v6;
      *reinterpret_cast<f32x4*>(dst + 7 * CSPL) = v7;
      asm volatile("s_waitcnt lgkmcnt(0)" ::: "memory");
      if (lane == 0) *(volatile int*)&ready[c] = 1;
    }
  }
}

// ---------------- 5. combine: P_b = sum_s alpha_400(s)*beta_400(s) ----------------
__global__ void combine_kernel(const float* __restrict__ abuf,
                               const int* __restrict__ kbuf,
                               float* __restrict__ out) {
  const int b = blockIdx.x;
  const int lane = threadIdx.x;
  f32x4 am = reinterpret_cast<const f32x4*>(abuf)[(b * 2 + 0) * 64 + lane];
  f32x4 bm = reinterpret_cast<const f32x4*>(abuf)[(b * 2 + 1) * 64 + lane];
  int ak = kbuf[(b * 2 + 0) * 64 + lane];
  int bk = kbuf[(b * 2 + 1) * 64 + lane];
  float val = am[0] * bm[0] + am[1] * bm[1] + am[2] * bm[2] + am[3] * bm[3];
  int e = (val > 0.f) ? (ak + bk) : (int)0xC0000000;   // -2^30 sentinel
  int E = e;
#pragma unroll
  for (int off = 32; off >= 1; off >>= 1) E = max(E, __shfl_xor(E, off));
  int t = e - E + 127;
  float f = t > 0 ? __builtin_bit_cast(float, t << 23) : 0.f;
  float c = val * f;
#pragma unroll
  for (int off = 32; off >= 1; off >>= 1) c += __shfl_xor(c, off);
  if (lane == 0) {
    float ll2 = flog2(c) + (float)E;             // log2 likelihood
    atomicAdd(out, -ll2 * (LN2F / CBATCH));      // natural-log NLL
  }
}

// ---------------- launch ----------------
extern "C" void kernel_launch(void* const* d_in, const int* in_sizes, int n_in,
                              void* d_out, int out_size, void* d_ws, size_t ws_size,
                              hipStream_t stream) {
  const float* hpad = (const float*)d_in[0];
  const float* W    = (const float*)d_in[1];
  const float* bias = (const float*)d_in[2];
  const int* labels = (const int*)d_in[3];
  const int* ilens  = (const int*)d_in[4];
  const int* llens  = (const int*)d_in[5];
  float* out = (float*)d_out;

  char* ws = (char*)d_ws;
  size_t off = 0;
  auto alloc = [&](size_t bytes) -> void* {
    void* p = ws + off;
    off = (off + bytes + 255) & ~(size_t)255;
    return p;
  };
  unsigned short* Abf = (unsigned short*)alloc((size_t)CM * CD * 2);        // 26.2 MB
  unsigned short* Wbf = (unsigned short*)alloc((size_t)CV * CD * 2);        //  1.0 MB
  unsigned short* logits = (unsigned short*)alloc((size_t)CM * CV * 2);     // 52.4 MB bf16
  float* lpg  = (float*)alloc((size_t)(CM + 64) * CSPL * 4);                // 26.3 MB
  float* abuf = (float*)alloc((size_t)CBATCH * 2 * 64 * 4 * sizeof(float)); // 64 KB
  int*   kbuf = (int*)alloc((size_t)CBATCH * 2 * 64 * sizeof(int));         // 16 KB

  hipMemsetAsync(d_out, 0, sizeof(float), stream);

  cvt_kernel<<<(CM * CD / 4 + 255) / 256, 256, 0, stream>>>(hpad, Abf, CM * CD / 4);
  cvt_kernel<<<(CV * CD / 4 + 255) / 256, 256, 0, stream>>>(W, Wbf, CV * CD / 4);
  gemm_kernel<<<dim3(CM / 128, CV / 128), 256, 0, stream>>>(Abf, Wbf, bias, logits);
  lse_gather_kernel<<<CM / 4, 256, 0, stream>>>(logits, labels, lpg);
  ctc_kernel<<<CBATCH * 2, 256, 0, stream>>>(lpg, labels, ilens, llens, abuf, kbuf);
  combine_kernel<<<CBATCH, 64, 0, stream>>>(abuf, kbuf, out);
}